// Round 1
// baseline (202.852 us; speedup 1.0000x reference)
//
#include <hip/hip_runtime.h>
#include <math.h>

// Problem constants (match reference).
#define BDIM 4096
#define TDIM 2048
#define ROWS_PER_BLOCK 8
#define K1_BLOCKS (BDIM / ROWS_PER_BLOCK)   // 512

// gamma powers as exact compile-time folded constants
constexpr double gpow(int e) {
    double r = 1.0;
    for (int i = 0; i < e; ++i) r *= 0.99;
    return r;
}

__device__ __forceinline__ float logsig(float x) {
    // log(sigmoid(x)) = min(x,0) - log1p(exp(-|x|))  (matches jax.nn.log_sigmoid)
    return fminf(x, 0.0f) - log1pf(expf(-fabsf(x)));
}

// K1: per-row reverse discounted scan (c[t] = wr[t] + g*c[t+1]), write cum,
// accumulate per-block column partial sums of (cum - baseline).
__global__ __launch_bounds__(256) void k1_scan(
    const float* __restrict__ logits,
    const float* __restrict__ weight,
    const float* __restrict__ baselines,
    float* __restrict__ cum_out,
    float* __restrict__ partial)
{
    const int tid  = threadIdx.x;
    const int lane = tid & 63;
    const int wave = tid >> 6;
    const int t0   = tid * 8;          // 8 contiguous elements per thread

    const float G    = 0.99f;
    const float G8   = (float)gpow(8);
    const float G512 = (float)gpow(512);
    const float LOG2G = -0.014499569695115089f;  // log2(0.99)
    // gamma^(8-k) for k=0..7
    const float gk[8] = {(float)gpow(8), (float)gpow(7), (float)gpow(6), (float)gpow(5),
                         (float)gpow(4), (float)gpow(3), (float)gpow(2), (float)gpow(1)};

    __shared__ float wsum[4];

    float colacc[8];
#pragma unroll
    for (int k = 0; k < 8; ++k) colacc[k] = 0.0f;

    for (int r = 0; r < ROWS_PER_BLOCK; ++r) {
        const int row = blockIdx.x * ROWS_PER_BLOCK + r;
        const size_t base = (size_t)row * TDIM + t0;

        float4 x0 = *reinterpret_cast<const float4*>(logits + base);
        float4 x1 = *reinterpret_cast<const float4*>(logits + base + 4);
        float4 w0 = *reinterpret_cast<const float4*>(weight + base);
        float4 w1 = *reinterpret_cast<const float4*>(weight + base + 4);

        float wr[8];
        wr[0] = w0.x * logsig(x0.x); wr[1] = w0.y * logsig(x0.y);
        wr[2] = w0.z * logsig(x0.z); wr[3] = w0.w * logsig(x0.w);
        wr[4] = w1.x * logsig(x1.x); wr[5] = w1.y * logsig(x1.y);
        wr[6] = w1.z * logsig(x1.z); wr[7] = w1.w * logsig(x1.w);

        // local suffix scan: loc[k] = sum_{s>=k} g^(s-k) wr[s]
        float loc[8];
        loc[7] = wr[7];
#pragma unroll
        for (int k = 6; k >= 0; --k) loc[k] = fmaf(G, loc[k + 1], wr[k]);

        // wave-level weighted suffix scan over per-thread totals, factor g^8
        float v = loc[0];
        float f = G8;
#pragma unroll
        for (int o = 1; o < 64; o <<= 1) {
            float up = __shfl_down(v, (unsigned)o, 64);
            if (lane + o < 64) v = fmaf(f, up, v);
            f *= f;
        }

        // cross-wave carry via LDS (4 waves, factor g^512 per wave)
        if (r) __syncthreads();                // protect wsum reuse across rows
        if (lane == 0) wsum[wave] = v;
        __syncthreads();
        const float W1 = wsum[1], W2 = wsum[2], W3 = wsum[3];
        const float FC3 = W3;
        const float FC2 = fmaf(G512, FC3, W2);
        const float FC1 = fmaf(G512, FC2, W1);
        const float carry = (wave == 0) ? FC1 : (wave == 1) ? FC2 : (wave == 2) ? FC3 : 0.0f;

        // full suffix value at this thread's first element
        const float vfull = fmaf(exp2f((float)((64 - lane) * 8) * LOG2G), carry, v);
        // cumulative at element t0+8 (tail): next lane's vfull; lane 63 -> carry
        const float vn = __shfl_down(vfull, 1, 64);
        const float tail = (lane == 63) ? carry : vn;

        float c[8];
#pragma unroll
        for (int k = 0; k < 8; ++k) c[k] = fmaf(gk[k], tail, loc[k]);

        float4 c0 = make_float4(c[0], c[1], c[2], c[3]);
        float4 c1 = make_float4(c[4], c[5], c[6], c[7]);
        *reinterpret_cast<float4*>(cum_out + base)     = c0;
        *reinterpret_cast<float4*>(cum_out + base + 4) = c1;

        float4 b0 = *reinterpret_cast<const float4*>(baselines + base);
        float4 b1 = *reinterpret_cast<const float4*>(baselines + base + 4);
        colacc[0] += c[0] - b0.x; colacc[1] += c[1] - b0.y;
        colacc[2] += c[2] - b0.z; colacc[3] += c[3] - b0.w;
        colacc[4] += c[4] - b1.x; colacc[5] += c[5] - b1.y;
        colacc[6] += c[6] - b1.z; colacc[7] += c[7] - b1.w;
    }

    const size_t pbase = (size_t)blockIdx.x * TDIM + t0;
    *reinterpret_cast<float4*>(partial + pbase)     = make_float4(colacc[0], colacc[1], colacc[2], colacc[3]);
    *reinterpret_cast<float4*>(partial + pbase + 4) = make_float4(colacc[4], colacc[5], colacc[6], colacc[7]);
}

// K2: reduce 512 partials per column into colsum (16 slices of 32 each).
__global__ __launch_bounds__(256) void k2_colsum(
    const float* __restrict__ partial, float* __restrict__ colsum)
{
    const int gid   = blockIdx.x * 256 + threadIdx.x;   // 0..32767
    const int col   = gid & (TDIM - 1);
    const int slice = gid >> 11;                        // 0..15
    const float* p = partial + (size_t)slice * 32 * TDIM + col;
    float s = 0.0f;
#pragma unroll 4
    for (int i = 0; i < 32; ++i) s += p[(size_t)i * TDIM];
    atomicAdd(colsum + col, s);
}

// K3: objective[t] = sum_b clip(cum - baseline - mean, +-5) * log_probs
__global__ __launch_bounds__(256) void k3_obj(
    const float* __restrict__ cum,
    const float* __restrict__ baselines,
    const float* __restrict__ lp,
    const float* __restrict__ colsum,
    float* __restrict__ obj)
{
    const int col = blockIdx.x * 256 + threadIdx.x;
    const int r0  = blockIdx.y * 128;
    const float mean = colsum[col] * (1.0f / (float)BDIM);
    float acc = 0.0f;
    size_t idx = (size_t)r0 * TDIM + col;
#pragma unroll 4
    for (int r = 0; r < 128; ++r, idx += TDIM) {
        float a = cum[idx] - baselines[idx] - mean;
        a = fminf(fmaxf(a, -5.0f), 5.0f);
        acc = fmaf(a, lp[idx], acc);
    }
    atomicAdd(obj + col, acc);
}

extern "C" void kernel_launch(void* const* d_in, const int* in_sizes, int n_in,
                              void* d_out, int out_size, void* d_ws, size_t ws_size,
                              hipStream_t stream) {
    const float* log_probs = (const float*)d_in[0];   // [B,T]
    const float* logits    = (const float*)d_in[1];   // [B,T,1]
    const float* weight    = (const float*)d_in[2];   // [B,T]
    const float* baselines = (const float*)d_in[3];   // [B,T,1]

    float* out = (float*)d_out;
    float* obj = out;            // [T]
    float* cum = out + TDIM;     // [B,T]

    float* partial = (float*)d_ws;                         // 512*2048 floats = 4 MB
    float* colsum  = partial + (size_t)K1_BLOCKS * TDIM;   // 2048 floats

    hipMemsetAsync(obj, 0, TDIM * sizeof(float), stream);
    hipMemsetAsync(colsum, 0, TDIM * sizeof(float), stream);

    k1_scan<<<K1_BLOCKS, 256, 0, stream>>>(logits, weight, baselines, cum, partial);
    k2_colsum<<<128, 256, 0, stream>>>(partial, colsum);
    k3_obj<<<dim3(TDIM / 256, BDIM / 128), 256, 0, stream>>>(cum, baselines, log_probs, colsum, obj);
}